// Round 1
// baseline (1067.094 us; speedup 1.0000x reference)
//
#include <hip/hip_runtime.h>

#define NB 4
#define NH 16
#define SEQ 2048
#define DH 128
#define QT 128
#define KT 64
#define NT (SEQ / KT)
#define NTHREADS 512

typedef __attribute__((ext_vector_type(8))) _Float16 f16x8;
typedef __attribute__((ext_vector_type(4))) _Float16 f16x4;
typedef __attribute__((ext_vector_type(2))) _Float16 f16x2;
typedef __attribute__((ext_vector_type(4))) float f32x4;

static __device__ __forceinline__ f16x2 pkrtz(float x, float y) {
    return __builtin_bit_cast(f16x2, __builtin_amdgcn_cvt_pkrtz(x, y));
}
static __device__ __forceinline__ unsigned ubits(f16x2 v) {
    return __builtin_bit_cast(unsigned, v);
}

// scale 1/0.32 and log2(e) folded into Q at load time -> QK output is already in exp2 domain
static constexpr float CLOG2E = 3.125f * 1.44269504088896340736f;

// V^T LDS swizzle: row d (128 rows x 64 keys, no pad, row = 128B).
// 8-half block kb8 stored at kb8 ^ dmix(d); verified conflict-free for staging
// writes (8B per lane) and PV b64 reads.
static __device__ __forceinline__ int vt_off(int d, int kb8, int sub4) {
    int dmix = (d & 7) ^ ((d >> 3) & 7);
    return (d << 6) + ((kb8 ^ dmix) << 3) + (sub4 << 2);
}

// K-tile: row-major [64][128] halfs (256B rows, no pad). XOR swizzle (G4):
// half-index col ^= (row&7)<<3  (16B granules) -> b128 reads spread 8 rows
// across 8 distinct 16B slots; rows 8..15 alias 2-way (free, m136).
static __device__ __forceinline__ int k_off(int row, int colh) {
    return (row << 7) + (colh ^ ((row & 7) << 3));
}

__global__ __launch_bounds__(NTHREADS, 4)
void fattn_kernel(const float* __restrict__ Q, const float* __restrict__ K,
                  const float* __restrict__ V, float* __restrict__ O) {
    // double-buffered tiles: 2*(16KB K + 16KB V^T) = 65536 B -> 2 blocks/CU
    __shared__ _Float16 lk[2][KT * DH];
    __shared__ _Float16 lvt[2][DH * KT];

    const int tid  = threadIdx.x;
    const int wave = tid >> 6;
    const int lane = tid & 63;
    const int l15  = lane & 15;
    const int quad = lane >> 4;

    // XCD swizzle: all 16 Q-tiles of one (b,h) on one XCD (K/V L2 locality).
    const int blk = blockIdx.x;              // 0..1023
    const int j   = blk >> 3;                // 0..127
    const int bh  = (blk & 7) + 8 * (j >> 4);
    const int qt  = j & 15;

    const size_t base = (size_t)bh * SEQ * DH;
    const float* Qb = Q + base;
    const float* Kb = K + base;
    const float* Vb = V + base;
    float*       Ob = O + base;

    // ---- Q fragments, B-operand layout: lane holds Q[q = l15][d = ks*32 + quad*8 + j] ----
    f16x8 qf[4];
    {
        const int qrow = qt * QT + wave * 16 + l15;
        const float* qp = Qb + (size_t)qrow * DH + quad * 8;
#pragma unroll
        for (int ks = 0; ks < 4; ++ks) {
            float4 a = *(const float4*)(qp + ks * 32);
            float4 b = *(const float4*)(qp + ks * 32 + 4);
            f16x2 p0 = pkrtz(a.x * CLOG2E, a.y * CLOG2E);
            f16x2 p1 = pkrtz(a.z * CLOG2E, a.w * CLOG2E);
            f16x2 p2 = pkrtz(b.x * CLOG2E, b.y * CLOG2E);
            f16x2 p3 = pkrtz(b.z * CLOG2E, b.w * CLOG2E);
            qf[ks] = (f16x8){p0.x, p0.y, p1.x, p1.y, p2.x, p2.y, p3.x, p3.y};
        }
    }

    // O accumulator: lane holds O[q = quad*4+r][d = db*16 + l15]
    f32x4 oacc[8];
#pragma unroll
    for (int db = 0; db < 8; ++db) oacc[db] = (f32x4){0.f, 0.f, 0.f, 0.f};
    float m_i = -3.0e38f;   // softmax state of q-row = l15 (replicated over quads)
    float l_i = 0.f;

    // staging decomposition: 512 threads, K/V tile = 64 rows x 128 cols fp32
    const int c4  = tid & 31;   // float4 column
    const int r16 = tid >> 5;   // rows r16*4 .. r16*4+3

    float4 kpf[4], vpf[4];

    auto load_kv = [&](int row0) {
        const float* kp = Kb + (size_t)(row0 + r16 * 4) * DH + c4 * 4;
        const float* vp = Vb + (size_t)(row0 + r16 * 4) * DH + c4 * 4;
#pragma unroll
        for (int p = 0; p < 4; ++p) {
            kpf[p] = *(const float4*)(kp + (size_t)p * DH);
            vpf[p] = *(const float4*)(vp + (size_t)p * DH);
        }
    };

    auto stage_write = [&](int sb) {
        unsigned vh[4][2];
#pragma unroll
        for (int p = 0; p < 4; ++p) {
            const int r = r16 * 4 + p;
            uint2 kw;
            kw.x = ubits(pkrtz(kpf[p].x, kpf[p].y));
            kw.y = ubits(pkrtz(kpf[p].z, kpf[p].w));
            *(uint2*)&lk[sb][k_off(r, c4 * 4)] = kw;
            vh[p][0] = ubits(pkrtz(vpf[p].x, vpf[p].y));
            vh[p][1] = ubits(pkrtz(vpf[p].z, vpf[p].w));
        }
#pragma unroll
        for (int i = 0; i < 4; ++i) {        // column d = c4*4 + i, keys r16*4..+3
            const int jw = i >> 1, sh = (i & 1) * 16;
            unsigned e0 = (vh[0][jw] >> sh) & 0xFFFFu;
            unsigned e1 = (vh[1][jw] >> sh) & 0xFFFFu;
            unsigned e2 = (vh[2][jw] >> sh) & 0xFFFFu;
            unsigned e3 = (vh[3][jw] >> sh) & 0xFFFFu;
            uint2 w;
            w.x = e0 | (e1 << 16);
            w.y = e2 | (e3 << 16);
            const int d = c4 * 4 + i;
            *(uint2*)&lvt[sb][vt_off(d, r16 >> 1, r16 & 1)] = w;
        }
    };

    // ---- prologue: tile0 -> buf0; tile1 in regs; one barrier ----
    load_kv(0);
    stage_write(0);
    load_kv(KT);
    __syncthreads();

    for (int t = 0; t < NT; ++t) {
        const int cb = t & 1;

        // ---- S^T = K . Q^T from buf[cb]; lane: S[q = l15][key = g*16 + quad*4 + r] ----
        f32x4 sacc[4];
#pragma unroll
        for (int g = 0; g < 4; ++g) sacc[g] = (f32x4){0.f, 0.f, 0.f, 0.f};
        __builtin_amdgcn_s_setprio(1);
#pragma unroll
        for (int g = 0; g < 4; ++g) {
#pragma unroll
            for (int ks = 0; ks < 4; ++ks) {
                f16x8 kf = *(const f16x8*)&lk[cb][k_off(g * 16 + l15, ks * 32 + quad * 8)];
                sacc[g] = __builtin_amdgcn_mfma_f32_16x16x32_f16(kf, qf[ks], sacc[g], 0, 0, 0);
            }
        }
        __builtin_amdgcn_s_setprio(0);

        // ---- stage tile t+1 (regs, loaded 1 full iter ago) into idle buffer.
        //      Writes drain under the softmax VALU phase; barrier at end of the
        //      PREVIOUS iter already guaranteed buf[cb^1]'s readers finished. ----
        if (t + 1 < NT) stage_write(cb ^ 1);
        // ---- issue tile t+2 loads: a full iteration of latency cover ----
        if (t + 2 < NT) load_kv((t + 2) * KT);

        // ---- online softmax (exp2 domain); defer-max skips rescale on converged tiles ----
        float mx0 = fmaxf(fmaxf(sacc[0][0], sacc[0][1]), fmaxf(sacc[0][2], sacc[0][3]));
        float mx1 = fmaxf(fmaxf(sacc[1][0], sacc[1][1]), fmaxf(sacc[1][2], sacc[1][3]));
        float mx2 = fmaxf(fmaxf(sacc[2][0], sacc[2][1]), fmaxf(sacc[2][2], sacc[2][3]));
        float mx3 = fmaxf(fmaxf(sacc[3][0], sacc[3][1]), fmaxf(sacc[3][2], sacc[3][3]));
        float mx  = fmaxf(fmaxf(mx0, mx1), fmaxf(mx2, mx3));
        mx = fmaxf(mx, __shfl_xor(mx, 16));
        mx = fmaxf(mx, __shfl_xor(mx, 32));

        if (!__all(mx <= m_i + 8.0f)) {   // wave-uniform; P bounded by 2^8 in f16 otherwise
            const float mnew  = fmaxf(m_i, mx);
            const float alpha = __builtin_amdgcn_exp2f(m_i - mnew);
            m_i = mnew;
            l_i *= alpha;
            float af[4];
#pragma unroll
            for (int r = 0; r < 4; ++r) af[r] = __shfl(alpha, (lane & 48) | (quad * 4 + r));
#pragma unroll
            for (int db = 0; db < 8; ++db)
#pragma unroll
                for (int r = 0; r < 4; ++r) oacc[db][r] *= af[r];
        }

        float ps[4][4];
        float rs = 0.f;
#pragma unroll
        for (int g = 0; g < 4; ++g)
#pragma unroll
            for (int r = 0; r < 4; ++r) {
                ps[g][r] = __builtin_amdgcn_exp2f(sacc[g][r] - m_i);
                rs += ps[g][r];
            }
        rs += __shfl_xor(rs, 16);
        rs += __shfl_xor(rs, 32);
        l_i += rs;

        // ---- O += P.V via 16x16x16 mfma: A = P (in regs), B = V^T from buf[cb] ----
        f16x4 pf[4];
#pragma unroll
        for (int g = 0; g < 4; ++g)
            pf[g] = (f16x4){(_Float16)ps[g][0], (_Float16)ps[g][1],
                            (_Float16)ps[g][2], (_Float16)ps[g][3]};
        __builtin_amdgcn_s_setprio(1);
#pragma unroll
        for (int db = 0; db < 8; ++db) {
            const int d = db * 16 + l15;
#pragma unroll
            for (int g = 0; g < 4; ++g) {
                const int kb8 = g * 2 + (quad >> 1);
                f16x4 vb = *(const f16x4*)&lvt[cb][vt_off(d, kb8, quad & 1)];
                oacc[db] = __builtin_amdgcn_mfma_f32_16x16x16f16(pf[g], vb, oacc[db], 0, 0, 0);
            }
        }
        __builtin_amdgcn_s_setprio(0);

        // single barrier per tile: protects buf[cb] (re-written at iter t+2's stage)
        if (t + 1 < NT) __syncthreads();
    }

    // ---- epilogue: O = acc / l ----
    const float inv = 1.0f / l_i;
    float invr[4];
#pragma unroll
    for (int r = 0; r < 4; ++r) invr[r] = __shfl(inv, (lane & 48) | (quad * 4 + r));
#pragma unroll
    for (int db = 0; db < 8; ++db)
#pragma unroll
        for (int r = 0; r < 4; ++r) {
            const int row = qt * QT + wave * 16 + quad * 4 + r;
            const int col = db * 16 + l15;
            Ob[(size_t)row * DH + col] = oacc[db][r] * invr[r];
        }
}

extern "C" void kernel_launch(void* const* d_in, const int* in_sizes, int n_in,
                              void* d_out, int out_size, void* d_ws, size_t ws_size,
                              hipStream_t stream) {
    const float* Q = (const float*)d_in[0];
    const float* K = (const float*)d_in[1];
    const float* V = (const float*)d_in[2];
    float* O = (float*)d_out;
    // masks (d_in[3..5]) and dropout_p (d_in[6]) unused per reference.
    const int nblocks = NB * NH * (SEQ / QT);   // 64 * 16 = 1024
    fattn_kernel<<<dim3(nblocks), dim3(NTHREADS), 0, stream>>>(Q, K, V, O);
}

// Round 2
// 831.532 us; speedup vs baseline: 1.2833x; 1.2833x over previous
//
#include <hip/hip_runtime.h>

#define NB 4
#define NH 16
#define SEQ 2048
#define DH 128
#define QT 128
#define KT 64
#define NTHREADS 512
#define LKS 136   /* K-tile row stride in halfs: 272 B rows, 16B-aligned, conflict-free b128 reads */

typedef __attribute__((ext_vector_type(8))) _Float16 f16x8;
typedef __attribute__((ext_vector_type(4))) _Float16 f16x4;
typedef __attribute__((ext_vector_type(2))) _Float16 f16x2;
typedef __attribute__((ext_vector_type(4))) float f32x4;

static __device__ __forceinline__ f16x2 pkrtz(float x, float y) {
    return __builtin_bit_cast(f16x2, __builtin_amdgcn_cvt_pkrtz(x, y));
}
static __device__ __forceinline__ unsigned ubits(f16x2 v) {
    return __builtin_bit_cast(unsigned, v);
}

// scale 1/0.32 and log2(e) folded into Q at load time -> QK output is already in exp2 domain
static constexpr float CLOG2E = 3.125f * 1.44269504088896340736f;

// V^T LDS swizzle: row d (128 rows x 64 keys, no pad, row = 128B = 32 dwords).
// 8-half block kb8 stored at kb8 ^ dmix(d); verified conflict-free for staging
// writes (8B per lane) and PV b64 reads.
static __device__ __forceinline__ int vt_off(int d, int kb8, int sub4) {
    int dmix = (d & 7) ^ ((d >> 3) & 7);
    return (d << 6) + ((kb8 ^ dmix) << 3) + (sub4 << 2);
}

__global__ __launch_bounds__(NTHREADS, 4)
void fattn_kernel(const float* __restrict__ Q, const float* __restrict__ K,
                  const float* __restrict__ V, float* __restrict__ O) {
    __shared__ _Float16 lk[KT][LKS];     // K tile, row-major [key][d], fp16
    __shared__ _Float16 lvt[DH * KT];    // V^T tile, swizzled, fp16

    const int tid  = threadIdx.x;
    const int wave = tid >> 6;
    const int lane = tid & 63;
    const int l15  = lane & 15;
    const int quad = lane >> 4;

    // XCD swizzle: all 16 Q-tiles of one (b,h) on one XCD (K/V L2 locality).
    const int blk = blockIdx.x;              // 0..1023
    const int j   = blk >> 3;                // 0..127
    const int bh  = (blk & 7) + 8 * (j >> 4);
    const int qt  = j & 15;

    const size_t base = (size_t)bh * SEQ * DH;
    const float* Qb = Q + base;
    const float* Kb = K + base;
    const float* Vb = V + base;
    float*       Ob = O + base;

    // ---- Q fragments, B-operand layout: lane holds Q[q = l15][d = ks*32 + quad*8 + j] ----
    // Pre-scaled by CLOG2E so S^T comes out in the exp2 domain.
    f16x8 qf[4];
    {
        const int qrow = qt * QT + wave * 16 + l15;
        const float* qp = Qb + (size_t)qrow * DH + quad * 8;
#pragma unroll
        for (int ks = 0; ks < 4; ++ks) {
            float4 a = *(const float4*)(qp + ks * 32);
            float4 b = *(const float4*)(qp + ks * 32 + 4);
            f16x2 p0 = pkrtz(a.x * CLOG2E, a.y * CLOG2E);
            f16x2 p1 = pkrtz(a.z * CLOG2E, a.w * CLOG2E);
            f16x2 p2 = pkrtz(b.x * CLOG2E, b.y * CLOG2E);
            f16x2 p3 = pkrtz(b.z * CLOG2E, b.w * CLOG2E);
            qf[ks] = (f16x8){p0.x, p0.y, p1.x, p1.y, p2.x, p2.y, p3.x, p3.y};
        }
    }

    // O accumulator: PV output C-layout: lane holds O[q = quad*4+r][d = db*16 + l15]
    f32x4 oacc[8];
#pragma unroll
    for (int db = 0; db < 8; ++db) oacc[db] = (f32x4){0.f, 0.f, 0.f, 0.f};
    float m_i = -3.0e38f;   // per-lane: softmax state of q-row = l15 (replicated over quads)
    float l_i = 0.f;

    // staging decomposition: 512 threads, K/V tile = 64 rows x 128 cols fp32
    const int c4  = tid & 31;   // float4 column
    const int r16 = tid >> 5;   // rows r16*4 .. r16*4+3

    // ---- preload tile 0 into registers ----
    float4 kpf[4], vpf[4];
    {
        const float* kp = Kb + (size_t)(r16 * 4) * DH + c4 * 4;
        const float* vp = Vb + (size_t)(r16 * 4) * DH + c4 * 4;
#pragma unroll
        for (int p = 0; p < 4; ++p) {
            kpf[p] = *(const float4*)(kp + (size_t)p * DH);
            vpf[p] = *(const float4*)(vp + (size_t)p * DH);
        }
    }

    for (int kt0 = 0; kt0 < SEQ; kt0 += KT) {
        __syncthreads();   // b1: previous tile's lk/lvt readers done

        // ---- stage K ONLY (half the old serial window); V staged later, under QK ----
#pragma unroll
        for (int p = 0; p < 4; ++p) {
            const int r = r16 * 4 + p;
            uint2 kw;
            kw.x = ubits(pkrtz(kpf[p].x, kpf[p].y));
            kw.y = ubits(pkrtz(kpf[p].z, kpf[p].w));
            *(uint2*)&lk[r][c4 * 4] = kw;
        }
        __syncthreads();   // b2: lk ready

        // ---- issue next tile's K loads (latency hides under QK + softmax) ----
        const bool more = (kt0 + KT) < SEQ;
        if (more) {
            const float* kp = Kb + (size_t)(kt0 + KT + r16 * 4) * DH + c4 * 4;
#pragma unroll
            for (int p = 0; p < 4; ++p) kpf[p] = *(const float4*)(kp + (size_t)p * DH);
        }

        // ---- S^T = K . Q^T : A = K-frag (m=key), B = Q-frag (n=q) ----
        // output lane: S[q = l15][key = g*16 + quad*4 + r]  == A-frag layout for PV!
        f32x4 sacc[4];
#pragma unroll
        for (int g = 0; g < 4; ++g) sacc[g] = (f32x4){0.f, 0.f, 0.f, 0.f};
        __builtin_amdgcn_s_setprio(1);
#pragma unroll
        for (int g = 0; g < 4; ++g) {
#pragma unroll
            for (int ks = 0; ks < 4; ++ks) {
                f16x8 kf = *(const f16x8*)&lk[g * 16 + l15][ks * 32 + quad * 8];
                sacc[g] = __builtin_amdgcn_mfma_f32_16x16x32_f16(kf, qf[ks], sacc[g], 0, 0, 0);
            }
        }
        __builtin_amdgcn_s_setprio(0);

        // ---- stage V (convert fp32->fp16, transpose, swizzled write).
        //      Overlaps other waves' QK (MFMA pipe); lvt readers of tile t-1
        //      finished at b1. lvt not read until after b3. ----
        {
            unsigned vh[4][2];
#pragma unroll
            for (int p = 0; p < 4; ++p) {
                vh[p][0] = ubits(pkrtz(vpf[p].x, vpf[p].y));
                vh[p][1] = ubits(pkrtz(vpf[p].z, vpf[p].w));
            }
#pragma unroll
            for (int i = 0; i < 4; ++i) {        // column d = c4*4 + i, keys r16*4..+3
                const int jw = i >> 1, sh = (i & 1) * 16;
                unsigned e0 = (vh[0][jw] >> sh) & 0xFFFFu;
                unsigned e1 = (vh[1][jw] >> sh) & 0xFFFFu;
                unsigned e2 = (vh[2][jw] >> sh) & 0xFFFFu;
                unsigned e3 = (vh[3][jw] >> sh) & 0xFFFFu;
                uint2 w;
                w.x = e0 | (e1 << 16);
                w.y = e2 | (e3 << 16);
                const int d = c4 * 4 + i;
                *(uint2*)&lvt[vt_off(d, r16 >> 1, r16 & 1)] = w;
            }
        }

        // ---- online softmax; defer-max skips rescale on converged tiles (verified r1) ----
        float mx0 = fmaxf(fmaxf(sacc[0][0], sacc[0][1]), fmaxf(sacc[0][2], sacc[0][3]));
        float mx1 = fmaxf(fmaxf(sacc[1][0], sacc[1][1]), fmaxf(sacc[1][2], sacc[1][3]));
        float mx2 = fmaxf(fmaxf(sacc[2][0], sacc[2][1]), fmaxf(sacc[2][2], sacc[2][3]));
        float mx3 = fmaxf(fmaxf(sacc[3][0], sacc[3][1]), fmaxf(sacc[3][2], sacc[3][3]));
        float mx  = fmaxf(fmaxf(mx0, mx1), fmaxf(mx2, mx3));
        mx = fmaxf(mx, __shfl_xor(mx, 16));
        mx = fmaxf(mx, __shfl_xor(mx, 32));

        if (!__all(mx <= m_i + 8.0f)) {   // wave-uniform; otherwise P bounded by 2^8, f16-safe
            const float mnew  = fmaxf(m_i, mx);
            const float alpha = __builtin_amdgcn_exp2f(m_i - mnew);
            m_i = mnew;
            l_i *= alpha;
            float af[4];
#pragma unroll
            for (int r = 0; r < 4; ++r) af[r] = __shfl(alpha, (lane & 48) | (quad * 4 + r));
#pragma unroll
            for (int db = 0; db < 8; ++db)
#pragma unroll
                for (int r = 0; r < 4; ++r) oacc[db][r] *= af[r];
        }

        float ps[4][4];
        float rs = 0.f;
#pragma unroll
        for (int g = 0; g < 4; ++g)
#pragma unroll
            for (int r = 0; r < 4; ++r) {
                ps[g][r] = __builtin_amdgcn_exp2f(sacc[g][r] - m_i);
                rs += ps[g][r];
            }
        rs += __shfl_xor(rs, 16);
        rs += __shfl_xor(rs, 32);
        l_i += rs;

        // ---- issue next tile's V loads (latency hides under PV) ----
        if (more) {
            const float* vp = Vb + (size_t)(kt0 + KT + r16 * 4) * DH + c4 * 4;
#pragma unroll
            for (int p = 0; p < 4; ++p) vpf[p] = *(const float4*)(vp + (size_t)p * DH);
        }

        __syncthreads();   // b3: lvt ready for all waves

        // ---- O += P.V via 16x16x16 mfma: A = P (in regs!), B = V^T from LDS ----
        f16x4 pf[4];
#pragma unroll
        for (int g = 0; g < 4; ++g)
            pf[g] = (f16x4){(_Float16)ps[g][0], (_Float16)ps[g][1],
                            (_Float16)ps[g][2], (_Float16)ps[g][3]};
        __builtin_amdgcn_s_setprio(1);
#pragma unroll
        for (int db = 0; db < 8; ++db) {
            const int d = db * 16 + l15;
#pragma unroll
            for (int g = 0; g < 4; ++g) {
                const int kb8 = g * 2 + (quad >> 1);
                f16x4 vb = *(const f16x4*)&lvt[vt_off(d, kb8, quad & 1)];
                oacc[db] = __builtin_amdgcn_mfma_f32_16x16x16f16(pf[g], vb, oacc[db], 0, 0, 0);
            }
        }
        __builtin_amdgcn_s_setprio(0);
    }

    // ---- epilogue: O = acc / l  (l_i lives at q=l15 lanes; shuffle to C-layout rows) ----
    const float inv = 1.0f / l_i;
    float invr[4];
#pragma unroll
    for (int r = 0; r < 4; ++r) invr[r] = __shfl(inv, (lane & 48) | (quad * 4 + r));
#pragma unroll
    for (int db = 0; db < 8; ++db)
#pragma unroll
        for (int r = 0; r < 4; ++r) {
            const int row = qt * QT + wave * 16 + quad * 4 + r;
            const int col = db * 16 + l15;
            Ob[(size_t)row * DH + col] = oacc[db][r] * invr[r];
        }
}

extern "C" void kernel_launch(void* const* d_in, const int* in_sizes, int n_in,
                              void* d_out, int out_size, void* d_ws, size_t ws_size,
                              hipStream_t stream) {
    const float* Q = (const float*)d_in[0];
    const float* K = (const float*)d_in[1];
    const float* V = (const float*)d_in[2];
    float* O = (float*)d_out;
    // masks (d_in[3..5]) and dropout_p (d_in[6]) unused per reference.
    const int nblocks = NB * NH * (SEQ / QT);   // 64 * 16 = 1024
    fattn_kernel<<<dim3(nblocks), dim3(NTHREADS), 0, stream>>>(Q, K, V, O);
}

// Round 3
// 715.984 us; speedup vs baseline: 1.4904x; 1.1614x over previous
//
#include <hip/hip_runtime.h>

#define NB 4
#define NH 16
#define SEQ 2048
#define DH 128
#define QT 128
#define KT 64
#define NTHREADS 512
#define LKS 136   /* K-tile row stride in halfs: 272 B rows, 16B-aligned, conflict-free b128 reads */

typedef __attribute__((ext_vector_type(8))) _Float16 f16x8;
typedef __attribute__((ext_vector_type(4))) _Float16 f16x4;
typedef __attribute__((ext_vector_type(2))) _Float16 f16x2;
typedef __attribute__((ext_vector_type(4))) float f32x4;

static __device__ __forceinline__ f16x2 pkrtz(float x, float y) {
    return __builtin_bit_cast(f16x2, __builtin_amdgcn_cvt_pkrtz(x, y));
}
static __device__ __forceinline__ unsigned ubits(f16x2 v) {
    return __builtin_bit_cast(unsigned, v);
}

// Barrier WITHOUT the vmcnt(0) drain __syncthreads() would emit.
// LDS producer->consumer visibility needs only lgkmcnt(0); global prefetch
// loads target registers, whose reads are guarded by compiler-inserted
// counted vmcnt waits. This keeps K/V prefetches in flight ACROSS barriers
// (the m97-ceiling "barrier drain" stall was the dominant cost).
static __device__ __forceinline__ void bar_lds() {
    asm volatile("s_waitcnt lgkmcnt(0)" ::: "memory");
    __builtin_amdgcn_s_barrier();
}

// scale 1/0.32 and log2(e) folded into Q at load time -> QK output is already in exp2 domain
static constexpr float CLOG2E = 3.125f * 1.44269504088896340736f;

// V^T LDS swizzle: row d (128 rows x 64 keys, no pad, row = 128B = 32 dwords).
// 8-half block kb8 stored at kb8 ^ dmix(d); verified conflict-free for staging
// writes (8B per lane) and PV b64 reads.
static __device__ __forceinline__ int vt_off(int d, int kb8, int sub4) {
    int dmix = (d & 7) ^ ((d >> 3) & 7);
    return (d << 6) + ((kb8 ^ dmix) << 3) + (sub4 << 2);
}

__global__ __launch_bounds__(NTHREADS, 4)
void fattn_kernel(const float* __restrict__ Q, const float* __restrict__ K,
                  const float* __restrict__ V, float* __restrict__ O) {
    __shared__ _Float16 lk[KT][LKS];     // K tile, row-major [key][d], fp16
    __shared__ _Float16 lvt[DH * KT];    // V^T tile, swizzled, fp16

    const int tid  = threadIdx.x;
    const int wave = tid >> 6;
    const int lane = tid & 63;
    const int l15  = lane & 15;
    const int quad = lane >> 4;

    // XCD swizzle: all 16 Q-tiles of one (b,h) on one XCD (K/V L2 locality).
    const int blk = blockIdx.x;              // 0..1023
    const int j   = blk >> 3;                // 0..127
    const int bh  = (blk & 7) + 8 * (j >> 4);
    const int qt  = j & 15;

    const size_t base = (size_t)bh * SEQ * DH;
    const float* Qb = Q + base;
    const float* Kb = K + base;
    const float* Vb = V + base;
    float*       Ob = O + base;

    // ---- Q fragments, B-operand layout: lane holds Q[q = l15][d = ks*32 + quad*8 + j] ----
    // Pre-scaled by CLOG2E so S^T comes out in the exp2 domain.
    f16x8 qf[4];
    {
        const int qrow = qt * QT + wave * 16 + l15;
        const float* qp = Qb + (size_t)qrow * DH + quad * 8;
#pragma unroll
        for (int ks = 0; ks < 4; ++ks) {
            float4 a = *(const float4*)(qp + ks * 32);
            float4 b = *(const float4*)(qp + ks * 32 + 4);
            f16x2 p0 = pkrtz(a.x * CLOG2E, a.y * CLOG2E);
            f16x2 p1 = pkrtz(a.z * CLOG2E, a.w * CLOG2E);
            f16x2 p2 = pkrtz(b.x * CLOG2E, b.y * CLOG2E);
            f16x2 p3 = pkrtz(b.z * CLOG2E, b.w * CLOG2E);
            qf[ks] = (f16x8){p0.x, p0.y, p1.x, p1.y, p2.x, p2.y, p3.x, p3.y};
        }
    }

    // O accumulator: PV output C-layout: lane holds O[q = quad*4+r][d = db*16 + l15]
    f32x4 oacc[8];
#pragma unroll
    for (int db = 0; db < 8; ++db) oacc[db] = (f32x4){0.f, 0.f, 0.f, 0.f};
    float m_i = -3.0e38f;   // per-lane: softmax state of q-row = l15 (replicated over quads)
    float l_i = 0.f;

    // staging decomposition: 512 threads, K/V tile = 64 rows x 128 cols fp32
    const int c4  = tid & 31;   // float4 column
    const int r16 = tid >> 5;   // rows r16*4 .. r16*4+3

    // ---- preload tile 0 into registers ----
    float4 kpf[4], vpf[4];
    {
        const float* kp = Kb + (size_t)(r16 * 4) * DH + c4 * 4;
        const float* vp = Vb + (size_t)(r16 * 4) * DH + c4 * 4;
#pragma unroll
        for (int p = 0; p < 4; ++p) {
            kpf[p] = *(const float4*)(kp + (size_t)p * DH);
            vpf[p] = *(const float4*)(vp + (size_t)p * DH);
        }
    }

    for (int kt0 = 0; kt0 < SEQ; kt0 += KT) {
        bar_lds();   // b1: previous tile's readers done (no vmcnt drain!)

        // ---- write staged regs -> LDS (cvt fp32->fp16; V transposed + swizzled) ----
        unsigned vh[4][2];
#pragma unroll
        for (int p = 0; p < 4; ++p) {
            const int r = r16 * 4 + p;
            uint2 kw;
            kw.x = ubits(pkrtz(kpf[p].x, kpf[p].y));
            kw.y = ubits(pkrtz(kpf[p].z, kpf[p].w));
            *(uint2*)&lk[r][c4 * 4] = kw;
            vh[p][0] = ubits(pkrtz(vpf[p].x, vpf[p].y));
            vh[p][1] = ubits(pkrtz(vpf[p].z, vpf[p].w));
        }
#pragma unroll
        for (int i = 0; i < 4; ++i) {        // column d = c4*4 + i, keys r16*4..+3
            const int jw = i >> 1, sh = (i & 1) * 16;
            unsigned e0 = (vh[0][jw] >> sh) & 0xFFFFu;
            unsigned e1 = (vh[1][jw] >> sh) & 0xFFFFu;
            unsigned e2 = (vh[2][jw] >> sh) & 0xFFFFu;
            unsigned e3 = (vh[3][jw] >> sh) & 0xFFFFu;
            uint2 w;
            w.x = e0 | (e1 << 16);
            w.y = e2 | (e3 << 16);
            const int d = c4 * 4 + i;
            *(uint2*)&lvt[vt_off(d, r16 >> 1, r16 & 1)] = w;
        }
        bar_lds();   // b2: lk/lvt ready (no vmcnt drain!)

        // ---- issue next tile's K loads (latency hides under QK + softmax) ----
        const bool more = (kt0 + KT) < SEQ;
        if (more) {
            const float* kp = Kb + (size_t)(kt0 + KT + r16 * 4) * DH + c4 * 4;
#pragma unroll
            for (int p = 0; p < 4; ++p) kpf[p] = *(const float4*)(kp + (size_t)p * DH);
        }

        // ---- S^T = K . Q^T : A = K-frag (m=key), B = Q-frag (n=q) ----
        // output lane: S[q = l15][key = g*16 + quad*4 + r]  == A-frag layout for PV!
        f32x4 sacc[4];
#pragma unroll
        for (int g = 0; g < 4; ++g) sacc[g] = (f32x4){0.f, 0.f, 0.f, 0.f};
#pragma unroll
        for (int g = 0; g < 4; ++g) {
#pragma unroll
            for (int ks = 0; ks < 4; ++ks) {
                f16x8 kf = *(const f16x8*)&lk[g * 16 + l15][ks * 32 + quad * 8];
                sacc[g] = __builtin_amdgcn_mfma_f32_16x16x32_f16(kf, qf[ks], sacc[g], 0, 0, 0);
            }
        }

        // ---- online softmax: each lane owns full row q=l15 locally (16 vals) + 2 shuffles ----
        float mx = sacc[0][0];
#pragma unroll
        for (int g = 0; g < 4; ++g)
#pragma unroll
            for (int r = 0; r < 4; ++r) mx = fmaxf(mx, sacc[g][r]);
        mx = fmaxf(mx, __shfl_xor(mx, 16));
        mx = fmaxf(mx, __shfl_xor(mx, 32));
        const float mnew = fmaxf(m_i, mx);
        const float alpha = __builtin_amdgcn_exp2f(m_i - mnew);
        m_i = mnew;

        float ps[4][4];
        float rs = 0.f;
#pragma unroll
        for (int g = 0; g < 4; ++g)
#pragma unroll
            for (int r = 0; r < 4; ++r) {
                ps[g][r] = __builtin_amdgcn_exp2f(sacc[g][r] - m_i);
                rs += ps[g][r];
            }
        rs += __shfl_xor(rs, 16);
        rs += __shfl_xor(rs, 32);
        l_i = l_i * alpha + rs;

        // ---- issue next tile's V loads (latency hides under PV) ----
        if (more) {
            const float* vp = Vb + (size_t)(kt0 + KT + r16 * 4) * DH + c4 * 4;
#pragma unroll
            for (int p = 0; p < 4; ++p) vpf[p] = *(const float4*)(vp + (size_t)p * DH);
        }

        // ---- rescale O by alpha of its own rows (q = quad*4+r, fetched via shuffle) ----
        float af[4];
#pragma unroll
        for (int r = 0; r < 4; ++r) af[r] = __shfl(alpha, (lane & 48) | (quad * 4 + r));
#pragma unroll
        for (int db = 0; db < 8; ++db)
#pragma unroll
            for (int r = 0; r < 4; ++r) oacc[db][r] *= af[r];

        // ---- O += P.V via 16x16x16 mfma: A = P (in regs!), B = V^T from LDS ----
        f16x4 pf[4];
#pragma unroll
        for (int g = 0; g < 4; ++g)
            pf[g] = (f16x4){(_Float16)ps[g][0], (_Float16)ps[g][1],
                            (_Float16)ps[g][2], (_Float16)ps[g][3]};
#pragma unroll
        for (int db = 0; db < 8; ++db) {
            const int d = db * 16 + l15;
#pragma unroll
            for (int g = 0; g < 4; ++g) {
                const int kb8 = g * 2 + (quad >> 1);
                f16x4 vb = *(const f16x4*)&lvt[vt_off(d, kb8, quad & 1)];
                oacc[db] = __builtin_amdgcn_mfma_f32_16x16x16f16(pf[g], vb, oacc[db], 0, 0, 0);
            }
        }
    }

    // ---- epilogue: O = acc / l  (l_i lives at q=l15 lanes; shuffle to C-layout rows) ----
    const float inv = 1.0f / l_i;
    float invr[4];
#pragma unroll
    for (int r = 0; r < 4; ++r) invr[r] = __shfl(inv, (lane & 48) | (quad * 4 + r));
#pragma unroll
    for (int db = 0; db < 8; ++db)
#pragma unroll
        for (int r = 0; r < 4; ++r) {
            const int row = qt * QT + wave * 16 + quad * 4 + r;
            const int col = db * 16 + l15;
            Ob[(size_t)row * DH + col] = oacc[db][r] * invr[r];
        }
}

extern "C" void kernel_launch(void* const* d_in, const int* in_sizes, int n_in,
                              void* d_out, int out_size, void* d_ws, size_t ws_size,
                              hipStream_t stream) {
    const float* Q = (const float*)d_in[0];
    const float* K = (const float*)d_in[1];
    const float* V = (const float*)d_in[2];
    float* O = (float*)d_out;
    // masks (d_in[3..5]) and dropout_p (d_in[6]) unused per reference.
    const int nblocks = NB * NH * (SEQ / QT);   // 64 * 16 = 1024
    fattn_kernel<<<dim3(nblocks), dim3(NTHREADS), 0, stream>>>(Q, K, V, O);
}